// Round 1
// baseline (457.483 us; speedup 1.0000x reference)
//
#include <hip/hip_runtime.h>
#include <hip/hip_bf16.h>

// ---------------- CSR build ----------------

__global__ void hist_kernel(const int* __restrict__ row, int* __restrict__ cnt, int e) {
  int i = blockIdx.x * 256 + threadIdx.x;
  if (i < e) atomicAdd(&cnt[row[i]], 1);
}

__global__ void scan1_kernel(const int* __restrict__ cnt, int* __restrict__ off,
                             int* __restrict__ bsum, int n) {
  __shared__ int sh[1024];
  int tid = threadIdx.x;
  int i = blockIdx.x * 1024 + tid;
  int v = (i < n) ? cnt[i] : 0;
  sh[tid] = v;
  __syncthreads();
  for (int d = 1; d < 1024; d <<= 1) {
    int t = (tid >= d) ? sh[tid - d] : 0;
    __syncthreads();
    sh[tid] += t;
    __syncthreads();
  }
  if (i < n) off[i] = sh[tid] - v;       // exclusive within block
  if (tid == 1023) bsum[blockIdx.x] = sh[1023];
}

__global__ void scan2_kernel(int* bsum, int nb) {
  if (blockIdx.x == 0 && threadIdx.x == 0) {
    int run = 0;
    for (int b = 0; b < nb; b++) { int t = bsum[b]; bsum[b] = run; run += t; }
  }
}

__global__ void scan3_kernel(const int* __restrict__ bsum, int* __restrict__ off,
                             int* __restrict__ cursor, int n, int e) {
  int i = blockIdx.x * 1024 + threadIdx.x;
  if (i < n) { int o = off[i] + bsum[blockIdx.x]; off[i] = o; cursor[i] = o; }
  if (i == 0) off[n] = e;
}

__global__ void scatter_kernel(const int* __restrict__ row, const int* __restrict__ col,
                               int* __restrict__ cursor, int* __restrict__ scol, int e) {
  int i = blockIdx.x * 256 + threadIdx.x;
  if (i < e) { int r = row[i]; int pos = atomicAdd(&cursor[r], 1); scol[pos] = col[i]; }
}

// ---------------- GEMM1: [q | k | v_s | v_v] = s @ [Wq | Wkv] + bias; P = v_v * v ----------------
// grid (ceil(N/64), 8), block 256. Col tile 64 of 512 total outputs per node.
// Outputs: q (f32, [N,128]) ; nodebuf (bf16, per node 640 = [k(128) | v_s(128) | P(3*128)])

__global__ __launch_bounds__(256) void gemm1_kernel(
    const float* __restrict__ s, const float* __restrict__ Wq, const float* __restrict__ bq,
    const float* __restrict__ Wkv, const float* __restrict__ bkv, const float* __restrict__ v,
    float* __restrict__ q_out, __hip_bfloat16* __restrict__ nodebuf, int n)
{
  __shared__ float As[64][65];   // [row][k] padded
  __shared__ float Bs[64][64];   // [k][col]
  const int tid = threadIdx.x;
  const int tx = tid & 15, ty = tid >> 4;
  const int n0 = blockIdx.x * 64;
  const int c512 = blockIdx.y * 64;

  const float* __restrict__ W; const float* __restrict__ bias; int stride, cbase;
  if (c512 < 128) { W = Wq;  bias = bq;  stride = 128; cbase = c512; }
  else            { W = Wkv; bias = bkv; stride = 384; cbase = c512 - 128; }

  float acc[4][4];
  #pragma unroll
  for (int r = 0; r < 4; r++)
    #pragma unroll
    for (int j = 0; j < 4; j++) acc[r][j] = 0.f;

  for (int p = 0; p < 2; p++) {
    #pragma unroll
    for (int i = 0; i < 4; i++) {
      int ch = i * 256 + tid;
      int r = ch >> 4, k4 = ch & 15;
      float4 val = make_float4(0.f, 0.f, 0.f, 0.f);
      if (n0 + r < n) val = *(const float4*)(&s[(size_t)(n0 + r) * 128 + p * 64 + k4 * 4]);
      As[r][k4 * 4 + 0] = val.x; As[r][k4 * 4 + 1] = val.y;
      As[r][k4 * 4 + 2] = val.z; As[r][k4 * 4 + 3] = val.w;
    }
    #pragma unroll
    for (int i = 0; i < 4; i++) {
      int ch = i * 256 + tid;
      int kk = ch >> 4, c4 = ch & 15;
      float4 wv = *(const float4*)(&W[(size_t)(p * 64 + kk) * stride + cbase + c4 * 4]);
      *(float4*)(&Bs[kk][c4 * 4]) = wv;
    }
    __syncthreads();
    #pragma unroll 8
    for (int kk = 0; kk < 64; kk++) {
      float4 b = *(const float4*)(&Bs[kk][tx * 4]);
      #pragma unroll
      for (int r = 0; r < 4; r++) {
        float a = As[ty * 4 + r][kk];
        acc[r][0] += a * b.x; acc[r][1] += a * b.y;
        acc[r][2] += a * b.z; acc[r][3] += a * b.w;
      }
    }
    __syncthreads();
  }

  const int cloc = tx * 4;
  #pragma unroll
  for (int r = 0; r < 4; r++) {
    int nn = n0 + ty * 4 + r;
    if (nn >= n) continue;
    #pragma unroll
    for (int j = 0; j < 4; j++) {
      float val = acc[r][j] + bias[cbase + cloc + j];
      int c = c512 + cloc + j;
      if (c < 128) {
        q_out[(size_t)nn * 128 + c] = val;
      } else if (c < 256) {
        nodebuf[(size_t)nn * 640 + (c - 128)] = __float2bfloat16(val);
      } else if (c < 384) {
        nodebuf[(size_t)nn * 640 + 128 + (c - 256)] = __float2bfloat16(val);
      } else {
        int cc = c - 384;
        #pragma unroll
        for (int j3 = 0; j3 < 3; j3++) {
          float pv = val * v[((size_t)nn * 3 + j3) * 128 + cc];
          nodebuf[(size_t)nn * 640 + 256 + j3 * 128 + cc] = __float2bfloat16(pv);
        }
      }
    }
  }
}

// ---------------- Aggregation: per node, iterate its edges (CSR), accumulate ----------------
// grid N, block 128. Writes s_out (final) and agg_v (staged in d_out v region).

__global__ __launch_bounds__(128) void agg_kernel(
    const int* __restrict__ off, const int* __restrict__ scol,
    const float* __restrict__ q, const __hip_bfloat16* __restrict__ nodebuf,
    const float* __restrict__ s, float* __restrict__ s_out, float* __restrict__ aggv)
{
  const int nid = blockIdx.x;
  const int t = threadIdx.x;
  const float qa = q[(size_t)nid * 128 + t];
  float accs = s[(size_t)nid * 128 + t];
  float av0 = 0.f, av1 = 0.f, av2 = 0.f;
  __shared__ float red[2];

  const int beg = off[nid], end = off[nid + 1];
  for (int i = beg; i < end; i++) {
    int c = scol[i];
    const __hip_bfloat16* base = nodebuf + (size_t)c * 640;
    float kt = __bfloat162float(base[t]);
    float p = qa * kt;
    p += __shfl_down(p, 32);
    p += __shfl_down(p, 16);
    p += __shfl_down(p, 8);
    p += __shfl_down(p, 4);
    p += __shfl_down(p, 2);
    p += __shfl_down(p, 1);
    if ((t & 63) == 0) red[t >> 6] = p;
    __syncthreads();
    float w = red[0] + red[1];
    __syncthreads();
    accs += w * __bfloat162float(base[128 + t]);
    av0  += w * __bfloat162float(base[256 + t]);
    av1  += w * __bfloat162float(base[384 + t]);
    av2  += w * __bfloat162float(base[512 + t]);
  }
  s_out[(size_t)nid * 128 + t] = accs;
  aggv[((size_t)nid * 3 + 0) * 128 + t] = av0;
  aggv[((size_t)nid * 3 + 1) * 128 + t] = av1;
  aggv[((size_t)nid * 3 + 2) * 128 + t] = av2;
}

// ---------------- GEMM2: v_out = v + agg_v @ Wvec + bvec (in-place on d_out v region) ----------------
// grid ceil(3N/32), block 256. BM=32 rows, BN=128 (full width -> in-place safe per block).

__global__ __launch_bounds__(256) void gemm2_kernel(
    const float* __restrict__ Wvec, const float* __restrict__ bvec,
    const float* __restrict__ v, float* __restrict__ vout, int rows)
{
  __shared__ float As[32][65];     // [row][k] padded
  __shared__ float Bs[64][128];    // [k][col], one K-half at a time
  const int tid = threadIdx.x;
  const int tx = tid & 31, ty = tid >> 5;
  const int r0 = blockIdx.x * 32;

  float acc[4][4];
  #pragma unroll
  for (int r = 0; r < 4; r++)
    #pragma unroll
    for (int j = 0; j < 4; j++) acc[r][j] = 0.f;

  for (int p = 0; p < 2; p++) {
    #pragma unroll
    for (int i = 0; i < 2; i++) {
      int ch = i * 256 + tid;
      int r = ch >> 4, k4 = ch & 15;
      float4 val = make_float4(0.f, 0.f, 0.f, 0.f);
      if (r0 + r < rows) val = *(const float4*)(&vout[(size_t)(r0 + r) * 128 + p * 64 + k4 * 4]);
      As[r][k4 * 4 + 0] = val.x; As[r][k4 * 4 + 1] = val.y;
      As[r][k4 * 4 + 2] = val.z; As[r][k4 * 4 + 3] = val.w;
    }
    #pragma unroll
    for (int i = 0; i < 8; i++) {
      int ch = i * 256 + tid;
      int kk = ch >> 5, c4 = ch & 31;
      *(float4*)(&Bs[kk][c4 * 4]) =
          *(const float4*)(&Wvec[(size_t)(p * 64 + kk) * 128 + c4 * 4]);
    }
    __syncthreads();
    #pragma unroll 8
    for (int kk = 0; kk < 64; kk++) {
      float4 b = *(const float4*)(&Bs[kk][tx * 4]);
      #pragma unroll
      for (int r = 0; r < 4; r++) {
        float a = As[ty * 4 + r][kk];
        acc[r][0] += a * b.x; acc[r][1] += a * b.y;
        acc[r][2] += a * b.z; acc[r][3] += a * b.w;
      }
    }
    __syncthreads();
  }

  #pragma unroll
  for (int r = 0; r < 4; r++) {
    int rr = r0 + ty * 4 + r;
    if (rr >= rows) continue;
    #pragma unroll
    for (int j = 0; j < 4; j++) {
      int c = tx * 4 + j;
      vout[(size_t)rr * 128 + c] = acc[r][j] + v[(size_t)rr * 128 + c] + bvec[c];
    }
  }
}

// ---------------- launch ----------------

extern "C" void kernel_launch(void* const* d_in, const int* in_sizes, int n_in,
                              void* d_out, int out_size, void* d_ws, size_t ws_size,
                              hipStream_t stream)
{
  const float* s    = (const float*)d_in[0];
  const float* v    = (const float*)d_in[1];
  const int*   ei   = (const int*)d_in[2];
  const float* Wq   = (const float*)d_in[3];
  const float* bq   = (const float*)d_in[4];
  const float* Wkv  = (const float*)d_in[5];
  const float* bkv  = (const float*)d_in[6];
  const float* Wvec = (const float*)d_in[7];
  const float* bvec = (const float*)d_in[8];

  const int N = in_sizes[0] / 128;
  const int E = in_sizes[2] / 2;
  const int* row = ei;
  const int* col = ei + E;

  char* ws = (char*)d_ws;
  size_t o = 0;
  auto alloc = [&](size_t bytes) -> char* {
    char* p = ws + o;
    o = (o + bytes + 255) & ~(size_t)255;
    return p;
  };
  int* off    = (int*)alloc((size_t)(N + 1) * 4);
  int* cursor = (int*)alloc((size_t)N * 4);       // doubles as histogram counts
  int* bsum   = (int*)alloc(4096);
  int* scol   = (int*)alloc((size_t)E * 4);
  float* qbuf = (float*)alloc((size_t)N * 128 * 4);
  __hip_bfloat16* nodebuf = (__hip_bfloat16*)alloc((size_t)N * 640 * 2);

  float* s_out = (float*)d_out;
  float* aggv  = (float*)d_out + (size_t)N * 128;

  // CSR build
  hipMemsetAsync(cursor, 0, (size_t)N * 4, stream);
  hist_kernel<<<(E + 255) / 256, 256, 0, stream>>>(row, cursor, E);
  int nb = (N + 1023) / 1024;
  scan1_kernel<<<nb, 1024, 0, stream>>>(cursor, off, bsum, N);
  scan2_kernel<<<1, 64, 0, stream>>>(bsum, nb);
  scan3_kernel<<<nb, 1024, 0, stream>>>(bsum, off, cursor, N, E);
  scatter_kernel<<<(E + 255) / 256, 256, 0, stream>>>(row, col, cursor, scol, E);

  // node features
  dim3 g1((N + 63) / 64, 8);
  gemm1_kernel<<<g1, 256, 0, stream>>>(s, Wq, bq, Wkv, bkv, v, qbuf, nodebuf, N);

  // edge aggregation
  agg_kernel<<<N, 128, 0, stream>>>(off, scol, qbuf, nodebuf, s, s_out, aggv);

  // v_out GEMM (in-place on d_out v region)
  gemm2_kernel<<<(3 * N + 31) / 32, 256, 0, stream>>>(Wvec, bvec, v, aggv, 3 * N);
}

// Round 2
// 416.050 us; speedup vs baseline: 1.0996x; 1.0996x over previous
//
#include <hip/hip_runtime.h>
#include <hip/hip_bf16.h>

// ---------------- CSR build ----------------

__global__ void hist_kernel(const int* __restrict__ row, int* __restrict__ cnt, int e) {
  int i = blockIdx.x * 256 + threadIdx.x;
  if (i < e) atomicAdd(&cnt[row[i]], 1);
}

__global__ void scan1_kernel(const int* __restrict__ cnt, int* __restrict__ off,
                             int* __restrict__ bsum, int n) {
  __shared__ int sh[1024];
  int tid = threadIdx.x;
  int i = blockIdx.x * 1024 + tid;
  int v = (i < n) ? cnt[i] : 0;
  sh[tid] = v;
  __syncthreads();
  for (int d = 1; d < 1024; d <<= 1) {
    int t = (tid >= d) ? sh[tid - d] : 0;
    __syncthreads();
    sh[tid] += t;
    __syncthreads();
  }
  if (i < n) off[i] = sh[tid] - v;       // exclusive within block
  if (tid == 1023) bsum[blockIdx.x] = sh[1023];
}

__global__ void scan2_kernel(int* bsum, int nb) {
  if (blockIdx.x == 0 && threadIdx.x == 0) {
    int run = 0;
    for (int b = 0; b < nb; b++) { int t = bsum[b]; bsum[b] = run; run += t; }
  }
}

__global__ void scan3_kernel(const int* __restrict__ bsum, int* __restrict__ off,
                             int* __restrict__ cursor, int n, int e) {
  int i = blockIdx.x * 1024 + threadIdx.x;
  if (i < n) { int o = off[i] + bsum[blockIdx.x]; off[i] = o; cursor[i] = o; }
  if (i == 0) off[n] = e;
}

__global__ void scatter_kernel(const int* __restrict__ row, const int* __restrict__ col,
                               int* __restrict__ cursor, int* __restrict__ scol, int e) {
  int i = blockIdx.x * 256 + threadIdx.x;
  if (i < e) { int r = row[i]; int pos = atomicAdd(&cursor[r], 1); scol[pos] = col[i]; }
}

// ---------------- GEMM1: [q | k | v_s | v_v] = s @ [Wq | Wkv] + bias; P = v_v * v ----------------

__global__ __launch_bounds__(256) void gemm1_kernel(
    const float* __restrict__ s, const float* __restrict__ Wq, const float* __restrict__ bq,
    const float* __restrict__ Wkv, const float* __restrict__ bkv, const float* __restrict__ v,
    float* __restrict__ q_out, __hip_bfloat16* __restrict__ nodebuf, int n)
{
  __shared__ float As[64][65];   // [row][k] padded
  __shared__ float Bs[64][64];   // [k][col]
  const int tid = threadIdx.x;
  const int tx = tid & 15, ty = tid >> 4;
  const int n0 = blockIdx.x * 64;
  const int c512 = blockIdx.y * 64;

  const float* __restrict__ W; const float* __restrict__ bias; int stride, cbase;
  if (c512 < 128) { W = Wq;  bias = bq;  stride = 128; cbase = c512; }
  else            { W = Wkv; bias = bkv; stride = 384; cbase = c512 - 128; }

  float acc[4][4];
  #pragma unroll
  for (int r = 0; r < 4; r++)
    #pragma unroll
    for (int j = 0; j < 4; j++) acc[r][j] = 0.f;

  for (int p = 0; p < 2; p++) {
    #pragma unroll
    for (int i = 0; i < 4; i++) {
      int ch = i * 256 + tid;
      int r = ch >> 4, k4 = ch & 15;
      float4 val = make_float4(0.f, 0.f, 0.f, 0.f);
      if (n0 + r < n) val = *(const float4*)(&s[(size_t)(n0 + r) * 128 + p * 64 + k4 * 4]);
      As[r][k4 * 4 + 0] = val.x; As[r][k4 * 4 + 1] = val.y;
      As[r][k4 * 4 + 2] = val.z; As[r][k4 * 4 + 3] = val.w;
    }
    #pragma unroll
    for (int i = 0; i < 4; i++) {
      int ch = i * 256 + tid;
      int kk = ch >> 4, c4 = ch & 15;
      float4 wv = *(const float4*)(&W[(size_t)(p * 64 + kk) * stride + cbase + c4 * 4]);
      *(float4*)(&Bs[kk][c4 * 4]) = wv;
    }
    __syncthreads();
    #pragma unroll 8
    for (int kk = 0; kk < 64; kk++) {
      float4 b = *(const float4*)(&Bs[kk][tx * 4]);
      #pragma unroll
      for (int r = 0; r < 4; r++) {
        float a = As[ty * 4 + r][kk];
        acc[r][0] += a * b.x; acc[r][1] += a * b.y;
        acc[r][2] += a * b.z; acc[r][3] += a * b.w;
      }
    }
    __syncthreads();
  }

  const int cloc = tx * 4;
  #pragma unroll
  for (int r = 0; r < 4; r++) {
    int nn = n0 + ty * 4 + r;
    if (nn >= n) continue;
    #pragma unroll
    for (int j = 0; j < 4; j++) {
      float val = acc[r][j] + bias[cbase + cloc + j];
      int c = c512 + cloc + j;
      if (c < 128) {
        q_out[(size_t)nn * 128 + c] = val;
      } else if (c < 256) {
        nodebuf[(size_t)nn * 640 + (c - 128)] = __float2bfloat16(val);
      } else if (c < 384) {
        nodebuf[(size_t)nn * 640 + 128 + (c - 256)] = __float2bfloat16(val);
      } else {
        int cc = c - 384;
        #pragma unroll
        for (int j3 = 0; j3 < 3; j3++) {
          float pv = val * v[((size_t)nn * 3 + j3) * 128 + cc];
          nodebuf[(size_t)nn * 640 + 256 + j3 * 128 + cc] = __float2bfloat16(pv);
        }
      }
    }
  }
}

// ---------------- Aggregation: one WAVE per node, 4-edge ILP, no LDS/barriers ----------------

__device__ inline float2 bf2f(unsigned u) {
  float2 r;
  r.x = __uint_as_float((u & 0xffffu) << 16);
  r.y = __uint_as_float(u & 0xffff0000u);
  return r;
}

__global__ __launch_bounds__(256) void agg_kernel(
    const int* __restrict__ off, const int* __restrict__ scol,
    const float* __restrict__ q, const __hip_bfloat16* __restrict__ nodebuf,
    const float* __restrict__ s, float* __restrict__ s_out, float* __restrict__ aggv, int n)
{
  const int wid = threadIdx.x >> 6;
  const int lane = threadIdx.x & 63;
  const int nid = blockIdx.x * 4 + wid;
  if (nid >= n) return;

  const float2 qa = *(const float2*)(&q[(size_t)nid * 128 + lane * 2]);
  float2 accs = *(const float2*)(&s[(size_t)nid * 128 + lane * 2]);
  float2 av0 = make_float2(0.f, 0.f), av1 = make_float2(0.f, 0.f), av2 = make_float2(0.f, 0.f);

  const int beg = off[nid], end = off[nid + 1];
  int i = beg;

  for (; i + 4 <= end; i += 4) {
    const unsigned* b0 = (const unsigned*)(nodebuf + (size_t)scol[i + 0] * 640) + lane;
    const unsigned* b1 = (const unsigned*)(nodebuf + (size_t)scol[i + 1] * 640) + lane;
    const unsigned* b2 = (const unsigned*)(nodebuf + (size_t)scol[i + 2] * 640) + lane;
    const unsigned* b3 = (const unsigned*)(nodebuf + (size_t)scol[i + 3] * 640) + lane;

    // k gathers (4 edges in flight)
    unsigned ku0 = b0[0], ku1 = b1[0], ku2 = b2[0], ku3 = b3[0];
    // accumulate-side gathers issued early to overlap with the reduce
    unsigned vs0 = b0[64],  vs1 = b1[64],  vs2 = b2[64],  vs3 = b3[64];
    unsigned p00 = b0[128], p01 = b1[128], p02 = b2[128], p03 = b3[128];
    unsigned p10 = b0[192], p11 = b1[192], p12 = b2[192], p13 = b3[192];
    unsigned p20 = b0[256], p21 = b1[256], p22 = b2[256], p23 = b3[256];

    float2 k0 = bf2f(ku0), k1 = bf2f(ku1), k2 = bf2f(ku2), k3 = bf2f(ku3);
    float d0 = qa.x * k0.x + qa.y * k0.y;
    float d1 = qa.x * k1.x + qa.y * k1.y;
    float d2 = qa.x * k2.x + qa.y * k2.y;
    float d3 = qa.x * k3.x + qa.y * k3.y;
    #pragma unroll
    for (int m = 32; m >= 1; m >>= 1) {
      d0 += __shfl_xor(d0, m);
      d1 += __shfl_xor(d1, m);
      d2 += __shfl_xor(d2, m);
      d3 += __shfl_xor(d3, m);
    }

    float2 t;
    t = bf2f(vs0); accs.x += d0 * t.x; accs.y += d0 * t.y;
    t = bf2f(vs1); accs.x += d1 * t.x; accs.y += d1 * t.y;
    t = bf2f(vs2); accs.x += d2 * t.x; accs.y += d2 * t.y;
    t = bf2f(vs3); accs.x += d3 * t.x; accs.y += d3 * t.y;
    t = bf2f(p00); av0.x += d0 * t.x; av0.y += d0 * t.y;
    t = bf2f(p01); av0.x += d1 * t.x; av0.y += d1 * t.y;
    t = bf2f(p02); av0.x += d2 * t.x; av0.y += d2 * t.y;
    t = bf2f(p03); av0.x += d3 * t.x; av0.y += d3 * t.y;
    t = bf2f(p10); av1.x += d0 * t.x; av1.y += d0 * t.y;
    t = bf2f(p11); av1.x += d1 * t.x; av1.y += d1 * t.y;
    t = bf2f(p12); av1.x += d2 * t.x; av1.y += d2 * t.y;
    t = bf2f(p13); av1.x += d3 * t.x; av1.y += d3 * t.y;
    t = bf2f(p20); av2.x += d0 * t.x; av2.y += d0 * t.y;
    t = bf2f(p21); av2.x += d1 * t.x; av2.y += d1 * t.y;
    t = bf2f(p22); av2.x += d2 * t.x; av2.y += d2 * t.y;
    t = bf2f(p23); av2.x += d3 * t.x; av2.y += d3 * t.y;
  }

  for (; i < end; i++) {
    const unsigned* b0 = (const unsigned*)(nodebuf + (size_t)scol[i] * 640) + lane;
    unsigned ku0 = b0[0];
    unsigned vs0 = b0[64], p00 = b0[128], p10 = b0[192], p20 = b0[256];
    float2 k0 = bf2f(ku0);
    float d0 = qa.x * k0.x + qa.y * k0.y;
    #pragma unroll
    for (int m = 32; m >= 1; m >>= 1) d0 += __shfl_xor(d0, m);
    float2 t;
    t = bf2f(vs0); accs.x += d0 * t.x; accs.y += d0 * t.y;
    t = bf2f(p00); av0.x += d0 * t.x; av0.y += d0 * t.y;
    t = bf2f(p10); av1.x += d0 * t.x; av1.y += d0 * t.y;
    t = bf2f(p20); av2.x += d0 * t.x; av2.y += d0 * t.y;
  }

  *(float2*)(&s_out[(size_t)nid * 128 + lane * 2]) = accs;
  *(float2*)(&aggv[((size_t)nid * 3 + 0) * 128 + lane * 2]) = av0;
  *(float2*)(&aggv[((size_t)nid * 3 + 1) * 128 + lane * 2]) = av1;
  *(float2*)(&aggv[((size_t)nid * 3 + 2) * 128 + lane * 2]) = av2;
}

// ---------------- GEMM2: v_out = v + agg_v @ Wvec + bvec (in-place on d_out v region) ----------------

__global__ __launch_bounds__(256) void gemm2_kernel(
    const float* __restrict__ Wvec, const float* __restrict__ bvec,
    const float* __restrict__ v, float* __restrict__ vout, int rows)
{
  __shared__ float As[32][65];     // [row][k] padded
  __shared__ float Bs[64][128];    // [k][col], one K-half at a time
  const int tid = threadIdx.x;
  const int tx = tid & 31, ty = tid >> 5;
  const int r0 = blockIdx.x * 32;

  float acc[4][4];
  #pragma unroll
  for (int r = 0; r < 4; r++)
    #pragma unroll
    for (int j = 0; j < 4; j++) acc[r][j] = 0.f;

  for (int p = 0; p < 2; p++) {
    #pragma unroll
    for (int i = 0; i < 2; i++) {
      int ch = i * 256 + tid;
      int r = ch >> 4, k4 = ch & 15;
      float4 val = make_float4(0.f, 0.f, 0.f, 0.f);
      if (r0 + r < rows) val = *(const float4*)(&vout[(size_t)(r0 + r) * 128 + p * 64 + k4 * 4]);
      As[r][k4 * 4 + 0] = val.x; As[r][k4 * 4 + 1] = val.y;
      As[r][k4 * 4 + 2] = val.z; As[r][k4 * 4 + 3] = val.w;
    }
    #pragma unroll
    for (int i = 0; i < 8; i++) {
      int ch = i * 256 + tid;
      int kk = ch >> 5, c4 = ch & 31;
      *(float4*)(&Bs[kk][c4 * 4]) =
          *(const float4*)(&Wvec[(size_t)(p * 64 + kk) * 128 + c4 * 4]);
    }
    __syncthreads();
    #pragma unroll 8
    for (int kk = 0; kk < 64; kk++) {
      float4 b = *(const float4*)(&Bs[kk][tx * 4]);
      #pragma unroll
      for (int r = 0; r < 4; r++) {
        float a = As[ty * 4 + r][kk];
        acc[r][0] += a * b.x; acc[r][1] += a * b.y;
        acc[r][2] += a * b.z; acc[r][3] += a * b.w;
      }
    }
    __syncthreads();
  }

  #pragma unroll
  for (int r = 0; r < 4; r++) {
    int rr = r0 + ty * 4 + r;
    if (rr >= rows) continue;
    #pragma unroll
    for (int j = 0; j < 4; j++) {
      int c = tx * 4 + j;
      vout[(size_t)rr * 128 + c] = acc[r][j] + v[(size_t)rr * 128 + c] + bvec[c];
    }
  }
}

// ---------------- launch ----------------

extern "C" void kernel_launch(void* const* d_in, const int* in_sizes, int n_in,
                              void* d_out, int out_size, void* d_ws, size_t ws_size,
                              hipStream_t stream)
{
  const float* s    = (const float*)d_in[0];
  const float* v    = (const float*)d_in[1];
  const int*   ei   = (const int*)d_in[2];
  const float* Wq   = (const float*)d_in[3];
  const float* bq   = (const float*)d_in[4];
  const float* Wkv  = (const float*)d_in[5];
  const float* bkv  = (const float*)d_in[6];
  const float* Wvec = (const float*)d_in[7];
  const float* bvec = (const float*)d_in[8];

  const int N = in_sizes[0] / 128;
  const int E = in_sizes[2] / 2;
  const int* row = ei;
  const int* col = ei + E;

  char* ws = (char*)d_ws;
  size_t o = 0;
  auto alloc = [&](size_t bytes) -> char* {
    char* p = ws + o;
    o = (o + bytes + 255) & ~(size_t)255;
    return p;
  };
  int* off    = (int*)alloc((size_t)(N + 1) * 4);
  int* cursor = (int*)alloc((size_t)N * 4);       // doubles as histogram counts
  int* bsum   = (int*)alloc(4096);
  int* scol   = (int*)alloc((size_t)E * 4);
  float* qbuf = (float*)alloc((size_t)N * 128 * 4);
  __hip_bfloat16* nodebuf = (__hip_bfloat16*)alloc((size_t)N * 640 * 2);

  float* s_out = (float*)d_out;
  float* aggv  = (float*)d_out + (size_t)N * 128;

  // CSR build
  hipMemsetAsync(cursor, 0, (size_t)N * 4, stream);
  hist_kernel<<<(E + 255) / 256, 256, 0, stream>>>(row, cursor, E);
  int nb = (N + 1023) / 1024;
  scan1_kernel<<<nb, 1024, 0, stream>>>(cursor, off, bsum, N);
  scan2_kernel<<<1, 64, 0, stream>>>(bsum, nb);
  scan3_kernel<<<nb, 1024, 0, stream>>>(bsum, off, cursor, N, E);
  scatter_kernel<<<(E + 255) / 256, 256, 0, stream>>>(row, col, cursor, scol, E);

  // node features
  dim3 g1((N + 63) / 64, 8);
  gemm1_kernel<<<g1, 256, 0, stream>>>(s, Wq, bq, Wkv, bkv, v, qbuf, nodebuf, N);

  // edge aggregation (one wave per node)
  agg_kernel<<<(N + 3) / 4, 256, 0, stream>>>(off, scol, qbuf, nodebuf, s, s_out, aggv, N);

  // v_out GEMM (in-place on d_out v region)
  gemm2_kernel<<<(3 * N + 31) / 32, 256, 0, stream>>>(Wvec, bvec, v, aggv, 3 * N);
}

// Round 3
// 388.046 us; speedup vs baseline: 1.1789x; 1.0722x over previous
//
#include <hip/hip_runtime.h>
#include <hip/hip_bf16.h>

typedef __attribute__((ext_vector_type(8))) __bf16 bf16x8;
typedef __attribute__((ext_vector_type(4))) float f32x4;

// ---------------- CSR build ----------------

__global__ void hist_kernel(const int* __restrict__ row, int* __restrict__ cnt, int e) {
  int i = blockIdx.x * 256 + threadIdx.x;
  if (i < e) atomicAdd(&cnt[row[i]], 1);
}

__global__ void scan1_kernel(const int* __restrict__ cnt, int* __restrict__ off,
                             int* __restrict__ bsum, int n) {
  __shared__ int sh[1024];
  int tid = threadIdx.x;
  int i = blockIdx.x * 1024 + tid;
  int v = (i < n) ? cnt[i] : 0;
  sh[tid] = v;
  __syncthreads();
  for (int d = 1; d < 1024; d <<= 1) {
    int t = (tid >= d) ? sh[tid - d] : 0;
    __syncthreads();
    sh[tid] += t;
    __syncthreads();
  }
  if (i < n) off[i] = sh[tid] - v;       // exclusive within block
  if (tid == 1023) bsum[blockIdx.x] = sh[1023];
}

__global__ void scan2_kernel(int* bsum, int nb) {
  if (blockIdx.x == 0 && threadIdx.x == 0) {
    int run = 0;
    for (int b = 0; b < nb; b++) { int t = bsum[b]; bsum[b] = run; run += t; }
  }
}

__global__ void scan3_kernel(const int* __restrict__ bsum, int* __restrict__ off,
                             int* __restrict__ cursor, int n, int e) {
  int i = blockIdx.x * 1024 + threadIdx.x;
  if (i < n) { int o = off[i] + bsum[blockIdx.x]; off[i] = o; cursor[i] = o; }
  if (i == 0) off[n] = e;
}

__global__ void scatter_kernel(const int* __restrict__ row, const int* __restrict__ col,
                               int* __restrict__ cursor, int* __restrict__ scol, int e) {
  int i = blockIdx.x * 256 + threadIdx.x;
  if (i < e) { int r = row[i]; int pos = atomicAdd(&cursor[r], 1); scol[pos] = col[i]; }
}

// ---------------- W prep: Wt[c][k] = bf16(W[k][c]), c in [0,512) unified q|kv ----------------

__global__ void wprep_kernel(const float* __restrict__ Wq, const float* __restrict__ Wkv,
                             __bf16* __restrict__ Wt) {
  int idx = blockIdx.x * 256 + threadIdx.x;      // 512*128 = 65536
  int c = idx >> 7, k = idx & 127;
  float w = (c < 128) ? Wq[k * 128 + c] : Wkv[k * 384 + (c - 128)];
  Wt[idx] = (__bf16)w;
}

// ---------------- GEMM1 (MFMA): 64 rows x 128 cols per block; K=128 in LDS ----------------
// blockIdx.y: 0 -> q (f32), 1 -> k (bf16), 2 -> v_s (bf16), 3 -> P = v_v*v (bf16 x3)

__global__ __launch_bounds__(256) void gemm1_mfma(
    const float* __restrict__ s, const __bf16* __restrict__ Wtg,
    const float* __restrict__ bq, const float* __restrict__ bkv,
    const float* __restrict__ v,
    float* __restrict__ q_out, __bf16* __restrict__ nodebuf, int n)
{
  __shared__ __bf16 sA[64 * 136];     // s tile, row stride 136 (272 B) -> bank-uniform b128
  __shared__ __bf16 sB[128 * 136];    // W^T chunk [col][k]

  const int tid = threadIdx.x;
  const int y = blockIdx.y;
  const int n0 = blockIdx.x * 64;

  // stage s rows -> bf16 LDS
  {
    int row = tid >> 2, seg = tid & 3;
    int gn = n0 + row;
    float4 f[8];
    if (gn < n) {
      #pragma unroll
      for (int i = 0; i < 8; i++)
        f[i] = *(const float4*)&s[(size_t)gn * 128 + seg * 32 + i * 4];
    } else {
      #pragma unroll
      for (int i = 0; i < 8; i++) f[i] = make_float4(0.f, 0.f, 0.f, 0.f);
    }
    #pragma unroll
    for (int i = 0; i < 4; i++) {
      bf16x8 pk;
      pk[0] = (__bf16)f[2*i].x;   pk[1] = (__bf16)f[2*i].y;
      pk[2] = (__bf16)f[2*i].z;   pk[3] = (__bf16)f[2*i].w;
      pk[4] = (__bf16)f[2*i+1].x; pk[5] = (__bf16)f[2*i+1].y;
      pk[6] = (__bf16)f[2*i+1].z; pk[7] = (__bf16)f[2*i+1].w;
      *(bf16x8*)&sA[row * 136 + seg * 32 + i * 8] = pk;
    }
  }
  // stage W^T chunk -> LDS
  {
    int row = tid >> 1, half = tid & 1;
    const __bf16* src = &Wtg[(size_t)(y * 128 + row) * 128 + half * 64];
    #pragma unroll
    for (int i = 0; i < 8; i++) {
      bf16x8 pk = *(const bf16x8*)&src[i * 8];
      *(bf16x8*)&sB[row * 136 + half * 64 + i * 8] = pk;
    }
  }
  __syncthreads();

  const int wave = tid >> 6, lane = tid & 63;
  const int lr = lane & 15, lg = lane >> 4;

  bf16x8 a[4];
  #pragma unroll
  for (int ks = 0; ks < 4; ks++)
    a[ks] = *(const bf16x8*)&sA[(wave * 16 + lr) * 136 + ks * 32 + lg * 8];

  f32x4 acc[8];
  #pragma unroll
  for (int cf = 0; cf < 8; cf++) {
    f32x4 c = {0.f, 0.f, 0.f, 0.f};
    #pragma unroll
    for (int ks = 0; ks < 4; ks++) {
      bf16x8 b = *(const bf16x8*)&sB[(cf * 16 + lr) * 136 + ks * 32 + lg * 8];
      c = __builtin_amdgcn_mfma_f32_16x16x32_bf16(a[ks], b, c, 0, 0, 0);
    }
    acc[cf] = c;
  }

  // epilogue: D row = (lane>>4)*4 + r, col = lane&15 (m89-verified)
  #pragma unroll
  for (int cf = 0; cf < 8; cf++) {
    int cl = cf * 16 + lr;
    #pragma unroll
    for (int r = 0; r < 4; r++) {
      int gn = n0 + wave * 16 + lg * 4 + r;
      if (gn >= n) continue;
      float val = acc[cf][r];
      if (y == 0) {
        q_out[(size_t)gn * 128 + cl] = val + bq[cl];
      } else if (y == 1) {
        nodebuf[(size_t)gn * 640 + cl] = (__bf16)(val + bkv[cl]);
      } else if (y == 2) {
        nodebuf[(size_t)gn * 640 + 128 + cl] = (__bf16)(val + bkv[128 + cl]);
      } else {
        float vv = val + bkv[256 + cl];
        #pragma unroll
        for (int j3 = 0; j3 < 3; j3++) {
          float pv = vv * v[((size_t)gn * 3 + j3) * 128 + cl];
          nodebuf[(size_t)gn * 640 + 256 + j3 * 128 + cl] = (__bf16)pv;
        }
      }
    }
  }
}

// ---------------- Aggregation: one WAVE per node, 4-edge ILP, no LDS/barriers ----------------

__device__ inline float2 bf2f(unsigned u) {
  float2 r;
  r.x = __uint_as_float((u & 0xffffu) << 16);
  r.y = __uint_as_float(u & 0xffff0000u);
  return r;
}

__global__ __launch_bounds__(256) void agg_kernel(
    const int* __restrict__ off, const int* __restrict__ scol,
    const float* __restrict__ q, const __hip_bfloat16* __restrict__ nodebuf,
    const float* __restrict__ s, float* __restrict__ s_out, float* __restrict__ aggv, int n)
{
  const int wid = threadIdx.x >> 6;
  const int lane = threadIdx.x & 63;
  const int nid = blockIdx.x * 4 + wid;
  if (nid >= n) return;

  const float2 qa = *(const float2*)(&q[(size_t)nid * 128 + lane * 2]);
  float2 accs = *(const float2*)(&s[(size_t)nid * 128 + lane * 2]);
  float2 av0 = make_float2(0.f, 0.f), av1 = make_float2(0.f, 0.f), av2 = make_float2(0.f, 0.f);

  const int beg = off[nid], end = off[nid + 1];
  int i = beg;

  for (; i + 4 <= end; i += 4) {
    const unsigned* b0 = (const unsigned*)(nodebuf + (size_t)scol[i + 0] * 640) + lane;
    const unsigned* b1 = (const unsigned*)(nodebuf + (size_t)scol[i + 1] * 640) + lane;
    const unsigned* b2 = (const unsigned*)(nodebuf + (size_t)scol[i + 2] * 640) + lane;
    const unsigned* b3 = (const unsigned*)(nodebuf + (size_t)scol[i + 3] * 640) + lane;

    unsigned ku0 = b0[0], ku1 = b1[0], ku2 = b2[0], ku3 = b3[0];
    unsigned vs0 = b0[64],  vs1 = b1[64],  vs2 = b2[64],  vs3 = b3[64];
    unsigned p00 = b0[128], p01 = b1[128], p02 = b2[128], p03 = b3[128];
    unsigned p10 = b0[192], p11 = b1[192], p12 = b2[192], p13 = b3[192];
    unsigned p20 = b0[256], p21 = b1[256], p22 = b2[256], p23 = b3[256];

    float2 k0 = bf2f(ku0), k1 = bf2f(ku1), k2 = bf2f(ku2), k3 = bf2f(ku3);
    float d0 = qa.x * k0.x + qa.y * k0.y;
    float d1 = qa.x * k1.x + qa.y * k1.y;
    float d2 = qa.x * k2.x + qa.y * k2.y;
    float d3 = qa.x * k3.x + qa.y * k3.y;
    #pragma unroll
    for (int m = 32; m >= 1; m >>= 1) {
      d0 += __shfl_xor(d0, m);
      d1 += __shfl_xor(d1, m);
      d2 += __shfl_xor(d2, m);
      d3 += __shfl_xor(d3, m);
    }

    float2 t;
    t = bf2f(vs0); accs.x += d0 * t.x; accs.y += d0 * t.y;
    t = bf2f(vs1); accs.x += d1 * t.x; accs.y += d1 * t.y;
    t = bf2f(vs2); accs.x += d2 * t.x; accs.y += d2 * t.y;
    t = bf2f(vs3); accs.x += d3 * t.x; accs.y += d3 * t.y;
    t = bf2f(p00); av0.x += d0 * t.x; av0.y += d0 * t.y;
    t = bf2f(p01); av0.x += d1 * t.x; av0.y += d1 * t.y;
    t = bf2f(p02); av0.x += d2 * t.x; av0.y += d2 * t.y;
    t = bf2f(p03); av0.x += d3 * t.x; av0.y += d3 * t.y;
    t = bf2f(p10); av1.x += d0 * t.x; av1.y += d0 * t.y;
    t = bf2f(p11); av1.x += d1 * t.x; av1.y += d1 * t.y;
    t = bf2f(p12); av1.x += d2 * t.x; av1.y += d2 * t.y;
    t = bf2f(p13); av1.x += d3 * t.x; av1.y += d3 * t.y;
    t = bf2f(p20); av2.x += d0 * t.x; av2.y += d0 * t.y;
    t = bf2f(p21); av2.x += d1 * t.x; av2.y += d1 * t.y;
    t = bf2f(p22); av2.x += d2 * t.x; av2.y += d2 * t.y;
    t = bf2f(p23); av2.x += d3 * t.x; av2.y += d3 * t.y;
  }

  for (; i < end; i++) {
    const unsigned* b0 = (const unsigned*)(nodebuf + (size_t)scol[i] * 640) + lane;
    unsigned ku0 = b0[0];
    unsigned vs0 = b0[64], p00 = b0[128], p10 = b0[192], p20 = b0[256];
    float2 k0 = bf2f(ku0);
    float d0 = qa.x * k0.x + qa.y * k0.y;
    #pragma unroll
    for (int m = 32; m >= 1; m >>= 1) d0 += __shfl_xor(d0, m);
    float2 t;
    t = bf2f(vs0); accs.x += d0 * t.x; accs.y += d0 * t.y;
    t = bf2f(p00); av0.x += d0 * t.x; av0.y += d0 * t.y;
    t = bf2f(p10); av1.x += d0 * t.x; av1.y += d0 * t.y;
    t = bf2f(p20); av2.x += d0 * t.x; av2.y += d0 * t.y;
  }

  *(float2*)(&s_out[(size_t)nid * 128 + lane * 2]) = accs;
  *(float2*)(&aggv[((size_t)nid * 3 + 0) * 128 + lane * 2]) = av0;
  *(float2*)(&aggv[((size_t)nid * 3 + 1) * 128 + lane * 2]) = av1;
  *(float2*)(&aggv[((size_t)nid * 3 + 2) * 128 + lane * 2]) = av2;
}

// ---------------- GEMM2: v_out = v + agg_v @ Wvec + bvec (in-place on d_out v region) ----------------

__global__ __launch_bounds__(256) void gemm2_kernel(
    const float* __restrict__ Wvec, const float* __restrict__ bvec,
    const float* __restrict__ v, float* __restrict__ vout, int rows)
{
  __shared__ float As[32][65];     // [row][k] padded
  __shared__ float Bs[64][128];    // [k][col], one K-half at a time
  const int tid = threadIdx.x;
  const int tx = tid & 31, ty = tid >> 5;
  const int r0 = blockIdx.x * 32;

  float acc[4][4];
  #pragma unroll
  for (int r = 0; r < 4; r++)
    #pragma unroll
    for (int j = 0; j < 4; j++) acc[r][j] = 0.f;

  for (int p = 0; p < 2; p++) {
    #pragma unroll
    for (int i = 0; i < 2; i++) {
      int ch = i * 256 + tid;
      int r = ch >> 4, k4 = ch & 15;
      float4 val = make_float4(0.f, 0.f, 0.f, 0.f);
      if (r0 + r < rows) val = *(const float4*)(&vout[(size_t)(r0 + r) * 128 + p * 64 + k4 * 4]);
      As[r][k4 * 4 + 0] = val.x; As[r][k4 * 4 + 1] = val.y;
      As[r][k4 * 4 + 2] = val.z; As[r][k4 * 4 + 3] = val.w;
    }
    #pragma unroll
    for (int i = 0; i < 8; i++) {
      int ch = i * 256 + tid;
      int kk = ch >> 5, c4 = ch & 31;
      *(float4*)(&Bs[kk][c4 * 4]) =
          *(const float4*)(&Wvec[(size_t)(p * 64 + kk) * 128 + c4 * 4]);
    }
    __syncthreads();
    #pragma unroll 8
    for (int kk = 0; kk < 64; kk++) {
      float4 b = *(const float4*)(&Bs[kk][tx * 4]);
      #pragma unroll
      for (int r = 0; r < 4; r++) {
        float a = As[ty * 4 + r][kk];
        acc[r][0] += a * b.x; acc[r][1] += a * b.y;
        acc[r][2] += a * b.z; acc[r][3] += a * b.w;
      }
    }
    __syncthreads();
  }

  #pragma unroll
  for (int r = 0; r < 4; r++) {
    int rr = r0 + ty * 4 + r;
    if (rr >= rows) continue;
    #pragma unroll
    for (int j = 0; j < 4; j++) {
      int c = tx * 4 + j;
      vout[(size_t)rr * 128 + c] = acc[r][j] + v[(size_t)rr * 128 + c] + bvec[c];
    }
  }
}

// ---------------- launch ----------------

extern "C" void kernel_launch(void* const* d_in, const int* in_sizes, int n_in,
                              void* d_out, int out_size, void* d_ws, size_t ws_size,
                              hipStream_t stream)
{
  const float* s    = (const float*)d_in[0];
  const float* v    = (const float*)d_in[1];
  const int*   ei   = (const int*)d_in[2];
  const float* Wq   = (const float*)d_in[3];
  const float* bq   = (const float*)d_in[4];
  const float* Wkv  = (const float*)d_in[5];
  const float* bkv  = (const float*)d_in[6];
  const float* Wvec = (const float*)d_in[7];
  const float* bvec = (const float*)d_in[8];

  const int N = in_sizes[0] / 128;
  const int E = in_sizes[2] / 2;
  const int* row = ei;
  const int* col = ei + E;

  char* ws = (char*)d_ws;
  size_t o = 0;
  auto alloc = [&](size_t bytes) -> char* {
    char* p = ws + o;
    o = (o + bytes + 255) & ~(size_t)255;
    return p;
  };
  int* off    = (int*)alloc((size_t)(N + 1) * 4);
  int* cursor = (int*)alloc((size_t)N * 4);       // doubles as histogram counts
  int* bsum   = (int*)alloc(4096);
  int* scol   = (int*)alloc((size_t)E * 4);
  float* qbuf = (float*)alloc((size_t)N * 128 * 4);
  __bf16* nodebuf = (__bf16*)alloc((size_t)N * 640 * 2);
  __bf16* Wt  = (__bf16*)alloc((size_t)512 * 128 * 2);

  float* s_out = (float*)d_out;
  float* aggv  = (float*)d_out + (size_t)N * 128;

  // CSR build
  hipMemsetAsync(cursor, 0, (size_t)N * 4, stream);
  hist_kernel<<<(E + 255) / 256, 256, 0, stream>>>(row, cursor, E);
  int nb = (N + 1023) / 1024;
  scan1_kernel<<<nb, 1024, 0, stream>>>(cursor, off, bsum, N);
  scan2_kernel<<<1, 64, 0, stream>>>(bsum, nb);
  scan3_kernel<<<nb, 1024, 0, stream>>>(bsum, off, cursor, N, E);
  scatter_kernel<<<(E + 255) / 256, 256, 0, stream>>>(row, col, cursor, scol, E);

  // weight prep + node features (MFMA)
  wprep_kernel<<<256, 256, 0, stream>>>(Wq, Wkv, Wt);
  dim3 g1((N + 63) / 64, 4);
  gemm1_mfma<<<g1, 256, 0, stream>>>(s, Wt, bq, bkv, v, qbuf, nodebuf, N);

  // edge aggregation (one wave per node)
  agg_kernel<<<(N + 3) / 4, 256, 0, stream>>>(off, scol, qbuf, (const __hip_bfloat16*)nodebuf,
                                              s, s_out, aggv, N);

  // v_out GEMM (in-place on d_out v region)
  gemm2_kernel<<<(3 * N + 31) / 32, 256, 0, stream>>>(Wvec, bvec, v, aggv, 3 * N);
}